// Round 2
// 4942.150 us; speedup vs baseline: 2.4162x; 2.4162x over previous
//
#include <hip/hip_runtime.h>
#include <hip/hip_bf16.h>

// Problem constants
#define B_  2
#define T_  2048
#define C_  1024
#define H_  16
#define HD_ 64
#define SCALE_ 0.125f   // 1/sqrt(64)

// GEMM tiling
#define BM_ 128
#define BN_ 128
#define BK_ 32

__device__ __forceinline__ float bf2f(unsigned short u) {
    union { unsigned int i; float f; } c; c.i = ((unsigned int)u) << 16; return c.f;
}
__device__ __forceinline__ unsigned short f2bf(float f) {
    union { float f; unsigned int i; } c; c.f = f;
    unsigned int x = c.i;
    unsigned int r = (x + 0x7fffu + ((x >> 16) & 1u)) >> 16;
    return (unsigned short)r;
}

// load one scalar, either bf16 or f32 storage
template<bool BF16>
__device__ __forceinline__ float loadS(const void* p, size_t i) {
    if (BF16) return bf2f(((const unsigned short*)p)[i]);
    else      return ((const float*)p)[i];
}

// load 8 consecutive elements starting at element 8*i8
template<bool BF16>
__device__ __forceinline__ void load8(const void* p, size_t i8, float* o) {
    if (BF16) {
        uint4 u = ((const uint4*)p)[i8];
        const unsigned short* us = (const unsigned short*)&u;
        #pragma unroll
        for (int j = 0; j < 8; j++) o[j] = bf2f(us[j]);
    } else {
        const uint4* q = (const uint4*)p + (size_t)i8 * 2;
        uint4 a = q[0], b = q[1];
        const float* fa = (const float*)&a;
        const float* fb = (const float*)&b;
        #pragma unroll
        for (int j = 0; j < 4; j++) { o[j] = fa[j]; o[4 + j] = fb[j]; }
    }
}

// ---------------------------------------------------------------------------
// Kernel 0: dtype detector (unchanged). flag = 1 -> bf16 storage, 0 -> f32.
// ---------------------------------------------------------------------------
__global__ void detect_kernel(const unsigned short* __restrict__ w, int* __restrict__ flag) {
    __shared__ int cnt;
    if (threadIdx.x == 0) cnt = 0;
    __syncthreads();
    int c = 0;
    for (int i = threadIdx.x; i < 4096; i += 256) {
        unsigned short u = w[2 * i];        // even ushort index
        int e = (u >> 7) & 0xFF;
        if (e >= 0xC0) c++;
    }
    atomicAdd(&cnt, c);
    __syncthreads();
    if (threadIdx.x == 0) *flag = (cnt < 256) ? 1 : 0;
}

// ---------------------------------------------------------------------------
// Tiled-GEMM staging: load a [128 rows x BK_ cols] panel of a row-major
// [outer][C_] matrix into LDS TRANSPOSED as dst[BK_][128].
// 512 chunks of 8 elements; 2 chunks per thread.
// Transposed stores: per store-instr lanes hit 32 banks 2-way -> free (m136).
// ---------------------------------------------------------------------------
template<bool BF16>
__device__ __forceinline__ void stage_tile(
    const void* __restrict__ src, int outer0, int k0, float (*dst)[BM_])
{
    const int tid = threadIdx.x;
    #pragma unroll
    for (int c = 0; c < 2; c++) {
        const int chunk = tid + c * 256;   // 0..511
        const int row   = chunk >> 2;      // 0..127
        const int cc    = chunk & 3;       // 0..3 (8-elem chunk within BK_)
        float tmp[8];
        const size_t elem = (size_t)(outer0 + row) * C_ + k0 + cc * 8;
        load8<BF16>(src, elem / 8, tmp);
        #pragma unroll
        for (int j = 0; j < 8; j++) dst[cc * 8 + j][row] = tmp[j];
    }
}

// ---------------------------------------------------------------------------
// Kernel 1: fused QKV projection as register-blocked SGEMM.
// C[4096 x 3072] = x[4096 x 1024] @ [Wq;Wk;Wv]^T, scattered to [B,H,T,HD].
// grid = (4096/128, 3072/128) = (32, 24). 256 thr, 8x8 outputs/thread.
// ---------------------------------------------------------------------------
template<bool BF16>
__device__ void qkv_gemm_body(
    const void* __restrict__ x,
    const void* __restrict__ Wq, const void* __restrict__ bq,
    const void* __restrict__ Wk, const void* __restrict__ bk,
    const void* __restrict__ Wv, const void* __restrict__ bv,
    float* __restrict__ qout, float* __restrict__ kout, float* __restrict__ vout)
{
    __shared__ float As[BK_][BM_];
    __shared__ float Bs[BK_][BN_];

    const int tid   = threadIdx.x;
    const int m0    = blockIdx.x * BM_;          // row-tile base (0..4095)
    const int in    = blockIdx.y;                // 0..23
    const int mat   = in >> 3;                   // 0=q 1=k 2=v
    const int nloc0 = (in & 7) * BN_;            // col base within the matrix

    const void* W    = (mat == 0) ? Wq : ((mat == 1) ? Wk : Wv);
    const void* bias = (mat == 0) ? bq : ((mat == 1) ? bk : bv);

    const int r0 = (tid >> 4) * 8;               // 0..120
    const int c0 = (tid & 15) * 8;               // 0..120

    float acc[8][8];
    #pragma unroll
    for (int i = 0; i < 8; i++)
        #pragma unroll
        for (int j = 0; j < 8; j++) acc[i][j] = 0.f;

    for (int k0 = 0; k0 < C_; k0 += BK_) {
        __syncthreads();
        stage_tile<BF16>(x, m0,    k0, As);
        stage_tile<BF16>(W, nloc0, k0, Bs);
        __syncthreads();

        #pragma unroll 4
        for (int kk = 0; kk < BK_; kk++) {
            const float4 a0 = *(const float4*)(&As[kk][r0]);
            const float4 a1 = *(const float4*)(&As[kk][r0 + 4]);
            const float4 b0 = *(const float4*)(&Bs[kk][c0]);
            const float4 b1 = *(const float4*)(&Bs[kk][c0 + 4]);
            const float av[8] = {a0.x, a0.y, a0.z, a0.w, a1.x, a1.y, a1.z, a1.w};
            const float bw[8] = {b0.x, b0.y, b0.z, b0.w, b1.x, b1.y, b1.z, b1.w};
            #pragma unroll
            for (int i = 0; i < 8; i++)
                #pragma unroll
                for (int j = 0; j < 8; j++)
                    acc[i][j] += av[i] * bw[j];
        }
    }

    float bvv[8];
    #pragma unroll
    for (int j = 0; j < 8; j++) bvv[j] = loadS<BF16>(bias, nloc0 + c0 + j);

    // this thread's 8 cols stay inside one head (c0 % 64 <= 56)
    const int c   = nloc0 + c0;
    const int hh  = c >> 6;
    const int hd0 = c & 63;
    float* outp = (mat == 0) ? qout : ((mat == 1) ? kout : vout);

    #pragma unroll
    for (int i = 0; i < 8; i++) {
        const int row = m0 + r0 + i;
        const int bb  = row >> 11;               // / T_
        const int tt  = row & (T_ - 1);
        float* d = outp + (((size_t)(bb * H_ + hh)) * T_ + tt) * HD_ + hd0;
        float4 o0, o1;
        o0.x = acc[i][0] + bvv[0]; o0.y = acc[i][1] + bvv[1];
        o0.z = acc[i][2] + bvv[2]; o0.w = acc[i][3] + bvv[3];
        o1.x = acc[i][4] + bvv[4]; o1.y = acc[i][5] + bvv[5];
        o1.z = acc[i][6] + bvv[6]; o1.w = acc[i][7] + bvv[7];
        *(float4*)d       = o0;
        *(float4*)(d + 4) = o1;
    }
}

__global__ __launch_bounds__(256) void qkv_kernel(
    const void* x,
    const void* Wq, const void* bq,
    const void* Wk, const void* bk,
    const void* Wv, const void* bv,
    const int* __restrict__ flag,
    float* qout, float* kout, float* vout)
{
    if (*flag) qkv_gemm_body<true >(x, Wq, bq, Wk, bk, Wv, bv, qout, kout, vout);
    else       qkv_gemm_body<false>(x, Wq, bq, Wk, bk, Wv, bv, qout, kout, vout);
}

// ---------------------------------------------------------------------------
// Kernel 2: attention (unchanged this round), one (b,h,q) row per block.
// ---------------------------------------------------------------------------
__global__ __launch_bounds__(256) void attn_kernel(
    const float* __restrict__ q, const float* __restrict__ k,
    const float* __restrict__ v,
    const void* __restrict__ hbias,   // [B,H,T,T] bf16 or f32
    const int* __restrict__ flag,
    float* __restrict__ y1)           // [B,T,C] f32
{
    const int mode = *flag;
    const int idx = blockIdx.x;
    const int qi  = idx & (T_ - 1);
    const int bh  = idx >> 11;
    const int hh  = bh & (H_ - 1);
    const int b   = bh >> 4;
    const int tid = threadIdx.x;

    __shared__ float qv[HD_];
    __shared__ float sc[T_];
    __shared__ float red[8];
    __shared__ float part[4][HD_];

    const float* qrow = q + ((size_t)bh * T_ + qi) * HD_;
    if (tid < HD_) qv[tid] = qrow[tid];
    __syncthreads();

    const float* kbase = k + (size_t)bh * T_ * HD_;
    const size_t hoff = ((size_t)bh * T_ + qi) * (size_t)T_;
    float lmax = -1e30f;
    if (mode) {
        const unsigned short* hrow = (const unsigned short*)hbias + hoff;
        for (int kk = tid; kk <= qi; kk += 256) {
            const float4* kr = (const float4*)(kbase + (size_t)kk * HD_);
            float dot = 0.f;
            #pragma unroll
            for (int i = 0; i < HD_ / 4; i++) {
                float4 f = kr[i];
                dot += qv[i * 4 + 0] * f.x + qv[i * 4 + 1] * f.y +
                       qv[i * 4 + 2] * f.z + qv[i * 4 + 3] * f.w;
            }
            float s = dot * SCALE_ + bf2f(hrow[kk]);
            sc[kk] = s;
            lmax = fmaxf(lmax, s);
        }
    } else {
        const float* hrow = (const float*)hbias + hoff;
        for (int kk = tid; kk <= qi; kk += 256) {
            const float4* kr = (const float4*)(kbase + (size_t)kk * HD_);
            float dot = 0.f;
            #pragma unroll
            for (int i = 0; i < HD_ / 4; i++) {
                float4 f = kr[i];
                dot += qv[i * 4 + 0] * f.x + qv[i * 4 + 1] * f.y +
                       qv[i * 4 + 2] * f.z + qv[i * 4 + 3] * f.w;
            }
            float s = dot * SCALE_ + hrow[kk];
            sc[kk] = s;
            lmax = fmaxf(lmax, s);
        }
    }
    #pragma unroll
    for (int off = 32; off > 0; off >>= 1)
        lmax = fmaxf(lmax, __shfl_down(lmax, off, 64));
    if ((tid & 63) == 0) red[tid >> 6] = lmax;
    __syncthreads();
    const float m = fmaxf(fmaxf(red[0], red[1]), fmaxf(red[2], red[3]));

    float lsum = 0.f;
    for (int kk = tid; kk <= qi; kk += 256) {
        float e = expf(sc[kk] - m);
        sc[kk] = e;
        lsum += e;
    }
    #pragma unroll
    for (int off = 32; off > 0; off >>= 1)
        lsum += __shfl_down(lsum, off, 64);
    if ((tid & 63) == 0) red[4 + (tid >> 6)] = lsum;
    __syncthreads();
    const float inv = 1.f / (red[4] + red[5] + red[6] + red[7]);

    const int d = tid & 63;
    const int s = tid >> 6;
    const float* vbase = v + (size_t)bh * T_ * HD_;
    float acc = 0.f;
    for (int kk = s; kk <= qi; kk += 4)
        acc += sc[kk] * vbase[(size_t)kk * HD_ + d];
    part[s][d] = acc;
    __syncthreads();
    if (tid < HD_) {
        float o = (part[0][tid] + part[1][tid] + part[2][tid] + part[3][tid]) * inv;
        y1[((size_t)(b * T_ + qi)) * C_ + hh * HD_ + tid] = o;
    }
}

// ---------------------------------------------------------------------------
// Kernel 3: output projection as register-blocked SGEMM.
// out[4096 x 1024] = y1[4096 x 1024] @ Wp^T + bp. grid = (32, 8).
// y1 is always f32 (internal); Wp/bp/out follow the dtype flag.
// ---------------------------------------------------------------------------
template<bool BF16>
__device__ void proj_gemm_body(
    const float* __restrict__ y1,
    const void* __restrict__ Wp, const void* __restrict__ bp,
    void* __restrict__ out)
{
    __shared__ float As[BK_][BM_];
    __shared__ float Bs[BK_][BN_];

    const int tid = threadIdx.x;
    const int m0  = blockIdx.x * BM_;
    const int n0  = blockIdx.y * BN_;

    const int r0 = (tid >> 4) * 8;
    const int c0 = (tid & 15) * 8;

    float acc[8][8];
    #pragma unroll
    for (int i = 0; i < 8; i++)
        #pragma unroll
        for (int j = 0; j < 8; j++) acc[i][j] = 0.f;

    for (int k0 = 0; k0 < C_; k0 += BK_) {
        __syncthreads();
        stage_tile<false>(y1, m0, k0, As);
        stage_tile<BF16>(Wp, n0, k0, Bs);
        __syncthreads();

        #pragma unroll 4
        for (int kk = 0; kk < BK_; kk++) {
            const float4 a0 = *(const float4*)(&As[kk][r0]);
            const float4 a1 = *(const float4*)(&As[kk][r0 + 4]);
            const float4 b0 = *(const float4*)(&Bs[kk][c0]);
            const float4 b1 = *(const float4*)(&Bs[kk][c0 + 4]);
            const float av[8] = {a0.x, a0.y, a0.z, a0.w, a1.x, a1.y, a1.z, a1.w};
            const float bw[8] = {b0.x, b0.y, b0.z, b0.w, b1.x, b1.y, b1.z, b1.w};
            #pragma unroll
            for (int i = 0; i < 8; i++)
                #pragma unroll
                for (int j = 0; j < 8; j++)
                    acc[i][j] += av[i] * bw[j];
        }
    }

    float bvv[8];
    #pragma unroll
    for (int j = 0; j < 8; j++) bvv[j] = loadS<BF16>(bp, n0 + c0 + j);

    #pragma unroll
    for (int i = 0; i < 8; i++) {
        const int row = m0 + r0 + i;
        const size_t off = (size_t)row * C_ + n0 + c0;
        if (BF16) {
            union { uint4 v; unsigned short us[8]; } pk;
            #pragma unroll
            for (int j = 0; j < 8; j++) pk.us[j] = f2bf(acc[i][j] + bvv[j]);
            *(uint4*)((unsigned short*)out + off) = pk.v;
        } else {
            float4 o0, o1;
            o0.x = acc[i][0] + bvv[0]; o0.y = acc[i][1] + bvv[1];
            o0.z = acc[i][2] + bvv[2]; o0.w = acc[i][3] + bvv[3];
            o1.x = acc[i][4] + bvv[4]; o1.y = acc[i][5] + bvv[5];
            o1.z = acc[i][6] + bvv[6]; o1.w = acc[i][7] + bvv[7];
            *(float4*)((float*)out + off)     = o0;
            *(float4*)((float*)out + off + 4) = o1;
        }
    }
}

__global__ __launch_bounds__(256) void proj_kernel(
    const float* y1, const void* Wp, const void* bp,
    const int* __restrict__ flag, void* out)
{
    if (*flag) proj_gemm_body<true >(y1, Wp, bp, out);
    else       proj_gemm_body<false>(y1, Wp, bp, out);
}

// ---------------------------------------------------------------------------
extern "C" void kernel_launch(void* const* d_in, const int* in_sizes, int n_in,
                              void* d_out, int out_size, void* d_ws, size_t ws_size,
                              hipStream_t stream)
{
    const void* x  = d_in[0];
    const void* h  = d_in[1];
    const void* Wq = d_in[2];
    const void* bq = d_in[3];
    const void* Wk = d_in[4];
    const void* bk = d_in[5];
    const void* Wv = d_in[6];
    const void* bv = d_in[7];
    const void* Wp = d_in[8];
    const void* bp = d_in[9];

    // ws layout: [flag header 256B][q 16MB][k 16MB][v 16MB][y1 16MB]
    int*   flag = (int*)d_ws;
    float* base = (float*)((char*)d_ws + 256);
    const size_t per = (size_t)B_ * H_ * T_ * HD_;   // 4M elems
    float* qws = base;
    float* kws = qws + per;
    float* vws = kws + per;
    float* y1  = vws + per;

    detect_kernel<<<1, 256, 0, stream>>>((const unsigned short*)Wq, flag);
    qkv_kernel<<<dim3(B_ * T_ / BM_, 24), 256, 0, stream>>>(
        x, Wq, bq, Wk, bk, Wv, bv, flag, qws, kws, vws);
    attn_kernel<<<dim3(B_ * H_ * T_), 256, 0, stream>>>(
        qws, kws, vws, h, flag, y1);
    proj_kernel<<<dim3(B_ * T_ / BM_, C_ / BN_), 256, 0, stream>>>(
        y1, Wp, bp, flag, (void*)d_out);
}